// Round 1
// baseline (3265.326 us; speedup 1.0000x reference)
//
#include <hip/hip_runtime.h>

// Problem constants (fixed by setup_inputs)
#define BB 32
#define NN 64
#define TT 11
#define FF 4
#define KK 2
#define EE 4032      // N*(N-1)
#define NSTEP 10

typedef _Float16 f16x8 __attribute__((ext_vector_type(8)));
typedef float    f32x4v __attribute__((ext_vector_type(4)));

// ---- stage kernel LDS (dynamic): u[2][64][512B, XOR-swizzled] + vb[2][2][256]f16 + wgt[2][128]f32
#define OFF_U    0
#define OFF_VB   65536
#define OFF_WGT  67584
#define SMEM2    68608

__device__ __forceinline__ float scrub(float v) {
    return fminf(fmaxf(v, -3.0e4f), 3.0e4f);   // inactive when correct (|x| <~ 600)
}

__device__ __forceinline__ float load_dt(const float* ts, const void* scp, int step) {
    float t0 = ts[step], t1 = ts[step + 1];
    int w = ((const int*)scp)[0];
    float scl;
    if (w > 0 && w < 1000000) scl = (float)w;            // int32 (live path)
    else {
        float f = __int_as_float(w);
        scl = (f > 0.5f && f < 1.0e6f) ? f : 10.0f;
    }
    return (t1 - t0) / scl;
}

typedef __attribute__((address_space(1))) const unsigned int glb_u32;
typedef __attribute__((address_space(3))) unsigned int lds_u32;
__device__ __forceinline__ void gload_lds16(const void* g, void* l) {
    __builtin_amdgcn_global_load_lds((glb_u32*)g, (lds_u32*)l, 16, 0, 0);
}

// ---- shared u/vb emission: u[b][k][n][256] f16 (row-XOR-swizzled bytes), vb linear ----
// u swizzle: within (b,k) slab, element (n,h) lives at byte n*512 + ((2h) ^ ((n&7)<<4)).
// Matches stage_kernel's ds_read pattern (16-lane groups gather 16 rows at same col -> 2-way max).
__device__ __forceinline__ void emit_uvb(int tid, int row0,
    const float (*smYn)[4],
    const float* __restrict__ W1g, const float* __restrict__ b1g,
    _Float16* __restrict__ uG, _Float16* __restrict__ vbG)
{
    const int hc = tid & 31, kk = (tid >> 5) & 1, rr = tid >> 6;
    const int h0 = hc * 8;
    const int row = row0 + rr;
    const int bb = row >> 6, n = row & 63;
    const float y0 = smYn[rr][0], y1 = smYn[rr][1], y2 = smYn[rr][2], y3 = smYn[rr][3];
    const float* wp = W1g + kk * 2048 + h0;
    const float* bp = b1g + kk * 256 + h0;
    f16x8 uu, vv;
    #pragma unroll
    for (int j = 0; j < 8; ++j) {
        float su = y0 * wp[j];
        su += y1 * wp[256 + j];
        su += y2 * wp[512 + j];
        su += y3 * wp[768 + j];
        float sv = bp[j];
        sv += y0 * wp[1024 + j];
        sv += y1 * wp[1280 + j];
        sv += y2 * wp[1536 + j];
        sv += y3 * wp[1792 + j];
        uu[j] = (_Float16)su;
        vv[j] = (_Float16)sv;
    }
    const size_t slab = ((size_t)bb * 2 + kk) * 16384;           // elements per (b,k)
    char* up = (char*)uG + slab * 2 + n * 512 + ((h0 * 2) ^ ((n & 7) << 4));
    *(f16x8*)up = uu;
    *(f16x8*)(vbG + slab + (size_t)n * 256 + h0) = vv;
}

// Edge-GEMM + aggregation for one RK4 stage. Block = (batch, 2 receivers).
// v2 (this round): u/vb precomputed by mlp_kernel (32x redundancy removed), staged via
// global_load_lds (zero-VALU staging, ONE barrier). Wave tile = 64 rows (one receiver)
// x 128 cols (ni=8): af reuse doubled -> af VALU + smU ds_reads per MFMA halved.
// b2 folded into acc init. Regs: acc 128 + af 16 + bfr 32 -> 2 waves/SIMD, 2 blocks/CU.
__global__ __launch_bounds__(256, 2)
void stage_kernel(const float* __restrict__ edges, const _Float16* __restrict__ W2F,
                  const float* __restrict__ b2g,
                  const _Float16* __restrict__ uG, const _Float16* __restrict__ vbG,
                  float* __restrict__ aggg)
{
    extern __shared__ char smem[];
    float* smWgt = (float*)(smem + OFF_WGT);

    const int tid  = threadIdx.x;
    const int b    = blockIdx.x >> 5;
    const int rg2  = blockIdx.x & 31;
    const int r0   = rg2 * 2;
    const int lane = tid & 63;
    const int wn   = tid >> 6;

    // ---- staging: u (64 KiB, both k) + vb (2 KiB) direct to LDS ----
    {
        const char* uGb = (const char*)(uG + (size_t)b * 2 * 16384);
        #pragma unroll
        for (int c = 0; c < 16; ++c) {
            int cc = wn + c * 4;
            gload_lds16(uGb + cc * 1024 + lane * 16, smem + OFF_U + cc * 1024);
        }
        if (wn < 2) {
            const char* vGb = (const char*)(vbG + ((size_t)b * 2 + wn) * 16384 + (size_t)r0 * 256);
            gload_lds16(vGb + lane * 16, smem + OFF_VB + wn * 1024);
        }
    }
    // ---- edge weights ----
    {
        int k = tid >> 7, m = tid & 127;        // m = rl*64 + jj
        int rl = m >> 6, jj = m & 63, rw = r0 + rl;
        float w = 0.0f;
        if (jj < 63) w = edges[((size_t)b * EE + rw * 63 + jj) * KK + k];
        smWgt[tid] = w;
    }

    const int rg   = wn >> 1;     // receiver within block (0/1)
    const int cg   = wn & 1;      // col half (0/1)
    const int ln15 = lane & 15;
    const int lg   = lane >> 4;   // 0..3
    const int r    = r0 + rg;

    // sender rows for this wave's 4 mi-tiles; precompute swizzled LDS offsets.
    // addr = s*512 + ((kc*64 + lg*16) ^ ((s&7)<<4)); split: bits 4-5 fold into base,
    // bit 6 XORs with kc*64 at read time.
    int uoffA[4], xmh[4];
    #pragma unroll
    for (int mi = 0; mi < 4; ++mi) {
        int jj = mi * 16 + ln15;
        int s = jj + (jj >= r ? 1 : 0);
        if (s > 63) s = 63;                     // jj==63 is the pad slot (wgt=0)
        int xm = (s & 7) << 4;
        uoffA[mi] = s * 512 + ((lg * 16) ^ (xm & 48));
        xmh[mi]   = xm & 64;
    }

    __syncthreads();   // drains vmcnt (global_load_lds) + LDS stores

    float rsum[8];
    #pragma unroll
    for (int ni = 0; ni < 8; ++ni) rsum[ni] = 0.0f;

    #pragma unroll 1
    for (int k = 0; k < KK; ++k) {
        const _Float16* bbase = W2F + ((size_t)((k * 16 + cg * 8) * 8)) * 512 + lane * 8;
        const char*  ubase = smem + OFF_U + k * 32768;
        const f16x8* vbase = (const f16x8*)(smem + OFF_VB + (k * 2 + rg) * 512);

        float bv[8];
        #pragma unroll
        for (int ni = 0; ni < 8; ++ni) bv[ni] = b2g[k * 256 + cg * 128 + ni * 16 + ln15];

        f32x4v acc[4][8];                       // bias folded into init
        #pragma unroll
        for (int mi = 0; mi < 4; ++mi)
            #pragma unroll
            for (int ni = 0; ni < 8; ++ni)
                acc[mi][ni] = (f32x4v){bv[ni], bv[ni], bv[ni], bv[ni]};

        #pragma unroll
        for (int kc = 0; kc < 8; ++kc) {
            f16x8 bfr[8];
            #pragma unroll
            for (int ni = 0; ni < 8; ++ni)
                bfr[ni] = *(const f16x8*)(bbase + (size_t)(ni * 8 + kc) * 512);
            f16x8 vbv = vbase[kc * 4 + lg];     // broadcast within 16-lane group
            f16x8 af[4]; f16x8 z = {};
            #pragma unroll
            for (int mi = 0; mi < 4; ++mi) {
                f16x8 uv = *(const f16x8*)(ubase + uoffA[mi] + ((kc * 64) ^ xmh[mi]));
                af[mi] = __builtin_elementwise_max(uv + vbv, z);
            }
            #pragma unroll
            for (int mi = 0; mi < 4; ++mi)
                #pragma unroll
                for (int ni = 0; ni < 8; ++ni)
                    acc[mi][ni] = __builtin_amdgcn_mfma_f32_16x16x32_f16(
                        af[mi], bfr[ni], acc[mi][ni], 0, 0, 0);
        }

        // ---- epilogue (per k): relu * edge_w, accumulate ----
        #pragma unroll
        for (int mi = 0; mi < 4; ++mi) {
            #pragma unroll
            for (int rr = 0; rr < 4; ++rr) {
                // C/D: col = lane&15, row = (lane>>4)*4 + rr  [m89/m91]
                float w = smWgt[k * 128 + rg * 64 + mi * 16 + lg * 4 + rr];
                #pragma unroll
                for (int ni = 0; ni < 8; ++ni)
                    rsum[ni] += fmaxf(acc[mi][ni][rr], 0.0f) * w;
            }
        }
    }

    // ---- cross-lane reduce over lg (rows) + direct global agg write ----
    #pragma unroll
    for (int ni = 0; ni < 8; ++ni) {
        rsum[ni] += __shfl_xor(rsum[ni], 16, 64);
        rsum[ni] += __shfl_xor(rsum[ni], 32, 64);
    }
    if (lane < 16) {
        #pragma unroll
        for (int ni = 0; ni < 8; ++ni)
            aggg[(size_t)(b * NN + r) * 256 + cg * 128 + ni * 16 + ln15] = rsum[ni];
    }
}

// Node MLP (f32-exact) + RK4 tail + u/vb emission for the NEXT stage.
__global__ __launch_bounds__(256, 4)
void mlp_kernel(int stage, int step,
    const float* __restrict__ Wo1, const float* __restrict__ bo1,
    const float* __restrict__ Wo2, const float* __restrict__ bo2,
    const float* __restrict__ Wo3, const float* __restrict__ bo3,
    const float* __restrict__ W1g, const float* __restrict__ b1g,
    const float* __restrict__ ts,  const void* __restrict__ scp,
    const float* __restrict__ xcur, const float* __restrict__ kprev,
    const float* __restrict__ aggg,
    float* __restrict__ kout,
    const float* __restrict__ k1b, const float* __restrict__ k2b,
    const float* __restrict__ k3b,
    float* __restrict__ xnext, float* __restrict__ outp,
    _Float16* __restrict__ uG, _Float16* __restrict__ vbG)
{
    __shared__ float smAug[4][264];    // 264 -> 16B-aligned rows
    __shared__ float smP1[4][256];
    __shared__ float smP2[4][256];
    __shared__ float smYn[4][4];

    const int tid  = threadIdx.x;
    const int row0 = blockIdx.x * 4;

    const float dt = load_dt(ts, scp, step);
    const float cc = (stage == 0) ? 0.0f : ((stage == 3) ? 1.0f : 0.5f);

    // ---- stage aug = [y(4) | agg(256)] per row ----
    for (int u = tid; u < 1040; u += 256) {
        int rr = u / 260, h = u - rr * 260;
        int row = row0 + rr;
        float v;
        if (h < 4) {
            int gi = row * 4 + h;
            v = xcur[gi];
            if (stage != 0) v += cc * dt * kprev[gi];
            v = scrub(v);
        } else {
            v = aggg[(size_t)row * 256 + (h - 4)];
        }
        smAug[rr][h] = v;
    }
    __syncthreads();

    // ---- L1: 260 -> 256, relu ----
    {
        int c = tid;
        float a[4];
        float b0 = bo1[c];
        #pragma unroll
        for (int rr = 0; rr < 4; ++rr) a[rr] = b0;
        #pragma unroll 1
        for (int hb = 0; hb < 256; hb += 8) {
            float w[8];
            #pragma unroll
            for (int j = 0; j < 8; ++j) w[j] = Wo1[(size_t)(hb + j) * 256 + c];
            f32x4v xlo[4], xhi[4];
            #pragma unroll
            for (int rr = 0; rr < 4; ++rr) {
                xlo[rr] = *(const f32x4v*)(&smAug[rr][hb]);
                xhi[rr] = *(const f32x4v*)(&smAug[rr][hb + 4]);
            }
            #pragma unroll
            for (int jj = 0; jj < 4; ++jj)
                #pragma unroll
                for (int rr = 0; rr < 4; ++rr) {
                    a[rr] += xlo[rr][jj] * w[jj];
                    a[rr] += xhi[rr][jj] * w[4 + jj];
                }
        }
        #pragma unroll
        for (int j = 0; j < 4; ++j) {          // tail h = 256..259
            float wv = Wo1[(size_t)(256 + j) * 256 + c];
            #pragma unroll
            for (int rr = 0; rr < 4; ++rr)
                a[rr] += smAug[rr][256 + j] * wv;
        }
        #pragma unroll
        for (int rr = 0; rr < 4; ++rr)
            smP1[rr][c] = fmaxf(a[rr], 0.0f);
    }
    __syncthreads();
    // ---- L2: 256 -> 256, relu ----
    {
        int c = tid;
        float a[4];
        float b0 = bo2[c];
        #pragma unroll
        for (int rr = 0; rr < 4; ++rr) a[rr] = b0;
        #pragma unroll 1
        for (int hb = 0; hb < 256; hb += 8) {
            float w[8];
            #pragma unroll
            for (int j = 0; j < 8; ++j) w[j] = Wo2[(size_t)(hb + j) * 256 + c];
            f32x4v xlo[4], xhi[4];
            #pragma unroll
            for (int rr = 0; rr < 4; ++rr) {
                xlo[rr] = *(const f32x4v*)(&smP1[rr][hb]);
                xhi[rr] = *(const f32x4v*)(&smP1[rr][hb + 4]);
            }
            #pragma unroll
            for (int jj = 0; jj < 4; ++jj)
                #pragma unroll
                for (int rr = 0; rr < 4; ++rr) {
                    a[rr] += xlo[rr][jj] * w[jj];
                    a[rr] += xhi[rr][jj] * w[4 + jj];
                }
        }
        #pragma unroll
        for (int rr = 0; rr < 4; ++rr)
            smP2[rr][c] = fmaxf(a[rr], 0.0f);
    }
    __syncthreads();
    // ---- L3 (256 -> 4) + residual + RK4 tail + y_next stash ----
    {
        int rr = tid >> 6, f = (tid >> 4) & 3, hs = tid & 15;
        float part = 0.0f;
        #pragma unroll
        for (int j = 0; j < 16; ++j) {
            int h = hs + j * 16;
            part += smP2[rr][h] * Wo3[h * 4 + f];
        }
        part += __shfl_xor(part, 8, 64);
        part += __shfl_xor(part, 4, 64);
        part += __shfl_xor(part, 2, 64);
        part += __shfl_xor(part, 1, 64);
        if (hs == 0) {
            int row = row0 + rr;
            int gi  = row * 4 + f;
            float y = xcur[gi];
            if (stage != 0) y += cc * dt * kprev[gi];
            y = scrub(y);
            float knew = scrub(y + bo3[f] + part);    // f(y) = y + p
            float yn;
            if (stage < 3) {
                kout[gi] = knew;
                float cn = (stage == 2) ? 1.0f : 0.5f;   // next stage's coefficient
                yn = scrub(xcur[gi] + cn * dt * knew);
            } else {
                float xn = scrub(xcur[gi] + (dt * (1.0f / 6.0f)) *
                           (k1b[gi] + 2.0f * k2b[gi] + 2.0f * k3b[gi] + knew));
                xnext[gi] = xn;
                // out layout (B, N, NSTEP, F): row = b*64+n
                outp[(size_t)row * NSTEP * FF + step * FF + f] = xn;
                yn = xn;                                 // next step stage 0: y = x
            }
            smYn[rr][f] = yn;
        }
    }
    __syncthreads();
    emit_uvb(tid, row0, smYn, W1g, b1g, uG, vbG);
}

// One-time u/vb init from x0 (step 0 stage 0).
__global__ __launch_bounds__(256)
void uvb_init(const float* __restrict__ xA,
              const float* __restrict__ W1g, const float* __restrict__ b1g,
              _Float16* __restrict__ uG, _Float16* __restrict__ vbG)
{
    __shared__ float smYn[4][4];
    const int tid  = threadIdx.x;
    const int row0 = blockIdx.x * 4;
    if (tid < 16) smYn[tid >> 2][tid & 3] = xA[row0 * 4 + tid];
    __syncthreads();
    emit_uvb(tid, row0, smYn, W1g, b1g, uG, vbG);
}

// Pre-swizzle W2 -> fragment-major W2F (verified round 7): chunk (k,ot,kc) is
// 1 KiB; lane l holds B[o = ot*16 + (l&15)][h = kc*32 + (l>>4)*8 + e]
__global__ void swizzle_w2(const float* __restrict__ W2, _Float16* __restrict__ W2F)
{
    int idx = blockIdx.x * 256 + threadIdx.x;       // 0 .. 131071
    int k   = idx >> 16;
    int rem = idx & 65535;
    int ch  = rem >> 9;
    int pos = rem & 511;
    int ot  = ch >> 3, kc = ch & 7;
    int l   = pos >> 3, e = pos & 7;
    int o   = ot * 16 + (l & 15);
    int h   = kc * 32 + (l >> 4) * 8 + e;
    W2F[idx] = (_Float16)W2[(size_t)(k * 256 + h) * 256 + o];
}

__global__ void init_x(const float* __restrict__ inp, float* __restrict__ x0)
{
    int i = blockIdx.x * 256 + threadIdx.x;   // i = (b*64+n)*4+f
    if (i < BB * NN * FF) {
        int f = i & 3, bn = i >> 2;
        x0[i] = scrub(inp[(size_t)(bn * TT) * FF + f]);   // inputs[b][n][0][f]
    }
}

static int find_input(const int* in_sizes, int n_in, int want, unsigned char* used, int dflt) {
    if (dflt >= 0 && dflt < n_in && in_sizes[dflt] == want && !used[dflt]) { used[dflt] = 1; return dflt; }
    for (int i = 0; i < n_in; ++i)
        if (!used[i] && in_sizes[i] == want) { used[i] = 1; return i; }
    return dflt;
}

extern "C" void kernel_launch(void* const* d_in, const int* in_sizes, int n_in,
                              void* d_out, int out_size, void* d_ws, size_t ws_size,
                              hipStream_t stream)
{
    unsigned char used[64] = {0};
    int iInp = find_input(in_sizes, n_in, BB*NN*TT*FF, used, 0);
    int iEdg = find_input(in_sizes, n_in, BB*EE*KK,    used, 1);
    (void)find_input(in_sizes, n_in, EE*NN, used, 2);              // rel_rec (unused)
    (void)find_input(in_sizes, n_in, EE*NN, used, 3);              // rel_send (unused)
    int iW1  = find_input(in_sizes, n_in, KK*8*256,  used, 4);
    int ib1  = find_input(in_sizes, n_in, KK*256,    used, 5);
    int iW2  = find_input(in_sizes, n_in, KK*256*256,used, 6);
    int ib2  = find_input(in_sizes, n_in, KK*256,    used, 7);
    int iWo1 = find_input(in_sizes, n_in, 260*256,   used, 8);
    int ibo1 = find_input(in_sizes, n_in, 256,       used, 9);
    int iWo2 = find_input(in_sizes, n_in, 256*256,   used, 10);
    int ibo2 = find_input(in_sizes, n_in, 256,       used, 11);
    int iWo3 = find_input(in_sizes, n_in, 256*4,     used, 12);
    int ibo3 = find_input(in_sizes, n_in, 4,         used, 13);
    int iTs  = find_input(in_sizes, n_in, TT,        used, 14);
    (void)find_input(in_sizes, n_in, 1, used, 15);                 // pred_steps
    int iSc  = find_input(in_sizes, n_in, 1,         used, 16);    // scale

    const float* inputs = (const float*)d_in[iInp];
    const float* edges  = (const float*)d_in[iEdg];
    const float* W1  = (const float*)d_in[iW1];
    const float* b1  = (const float*)d_in[ib1];
    const float* W2  = (const float*)d_in[iW2];
    const float* b2  = (const float*)d_in[ib2];
    const float* Wo1 = (const float*)d_in[iWo1];
    const float* bo1 = (const float*)d_in[ibo1];
    const float* Wo2 = (const float*)d_in[iWo2];
    const float* bo2 = (const float*)d_in[ibo2];
    const float* Wo3 = (const float*)d_in[iWo3];
    const float* bo3 = (const float*)d_in[ibo3];
    const float* ts  = (const float*)d_in[iTs];
    const void*  scp = d_in[iSc];

    char* ws = (char*)d_ws;
    _Float16* W2F = (_Float16*)ws;                     // 262144 B
    float* xA  = (float*)(ws + 262144);
    float* xB  = (float*)(ws + 262144 + 1 * 32768);
    float* k1  = (float*)(ws + 262144 + 2 * 32768);
    float* k2  = (float*)(ws + 262144 + 3 * 32768);
    float* k3  = (float*)(ws + 262144 + 4 * 32768);
    float* agg = (float*)(ws + 262144 + 5 * 32768);    // 2048*256*4 = 2 MiB
    _Float16* uG  = (_Float16*)(ws + 262144 + 5 * 32768 + 2097152);            // 2 MiB
    _Float16* vbG = (_Float16*)(ws + 262144 + 5 * 32768 + 2097152 + 2097152);  // 2 MiB

    float* outp = (float*)d_out;   // f32 output

    (void)hipFuncSetAttribute((const void*)stage_kernel,
        hipFuncAttributeMaxDynamicSharedMemorySize, SMEM2);

    swizzle_w2<<<dim3(512), dim3(256), 0, stream>>>(W2, W2F);
    init_x<<<dim3(32), dim3(256), 0, stream>>>(inputs, xA);
    uvb_init<<<dim3(512), dim3(256), 0, stream>>>(xA, W1, b1, uG, vbG);

    float* xc = xA;
    float* xn = xB;
    for (int step = 0; step < NSTEP; ++step) {
        float* kprevs[4] = { xc, k1, k2, k3 };   // kprev per stage (xc unused at s0)
        float* kouts[4]  = { k1, k2, k3, k3 };   // kout per stage (s3 -> tail path)
        for (int s = 0; s < 4; ++s) {
            stage_kernel<<<dim3(1024), dim3(256), SMEM2, stream>>>(
                edges, W2F, b2, uG, vbG, agg);
            mlp_kernel<<<dim3(512), dim3(256), 0, stream>>>(s, step,
                Wo1, bo1, Wo2, bo2, Wo3, bo3, W1, b1, ts, scp, xc, kprevs[s], agg,
                kouts[s], k1, k2, k3, xn, outp, uG, vbG);
        }
        float* t = xc; xc = xn; xn = t;
    }
}